// Round 6
// baseline (236.246 us; speedup 1.0000x reference)
//
#include <hip/hip_runtime.h>
#include <stdint.h>

typedef __attribute__((ext_vector_type(8))) short short8;
typedef __attribute__((ext_vector_type(4))) float f32x4;

#define NEG_FLT_MAX (-3.402823466e38f)

__device__ __forceinline__ unsigned short f2bf(float f) {
  uint32_t u = __float_as_uint(f);
  uint32_t r = (u + 0x7fffu + ((u >> 16) & 1u)) >> 16;
  return (unsigned short)r;
}

__device__ __forceinline__ void gload16(const void* g, void* l) {
  __builtin_amdgcn_global_load_lds(
      (const __attribute__((address_space(1))) uint32_t*)g,
      (__attribute__((address_space(3))) uint32_t*)l, 16, 0, 0);
}

// ---------------- merged weight transposes: fp32->bf16, [R][C] -> [C][R] ----------------
__global__ void tp3_kernel(const float* __restrict__ qw, const float* __restrict__ kw,
                           const float* __restrict__ vw,
                           unsigned short* __restrict__ qwt, unsigned short* __restrict__ kwt,
                           unsigned short* __restrict__ vwt, float kscale) {
  __shared__ float tile[32][33];
  const int z = blockIdx.z;
  const float* src = (z == 0) ? qw : (z == 1) ? kw : vw;
  unsigned short* dst = (z == 0) ? qwt : (z == 1) ? kwt : vwt;
  const int R = (z == 0) ? 1024 : 1536;
  const float scale = (z == 1) ? kscale : 1.0f;
  const int C = 1024;
  const int c0 = blockIdx.x * 32;
  const int r0 = blockIdx.y * 32;
  if (r0 >= R) return;
  const int tx = threadIdx.x, ty = threadIdx.y;  // 32 x 8
#pragma unroll
  for (int i = ty; i < 32; i += 8)
    tile[i][tx] = src[(size_t)(r0 + i) * C + (c0 + tx)];
  __syncthreads();
#pragma unroll
  for (int i = ty; i < 32; i += 8)
    dst[(size_t)(c0 + i) * R + (r0 + tx)] = f2bf(tile[tx][i] * scale);
}

// ---------------- block reduction helper ----------------
__device__ __forceinline__ void block_reduce2(float& s, float& ss, float* red) {
#pragma unroll
  for (int off = 32; off > 0; off >>= 1) {
    s += __shfl_xor(s, off);
    ss += __shfl_xor(ss, off);
  }
  const int wave = threadIdx.x >> 6;
  const int lane = threadIdx.x & 63;
  if (lane == 0) { red[wave * 2] = s; red[wave * 2 + 1] = ss; }
  __syncthreads();
  if (threadIdx.x == 0) {
    float a = 0.f, b = 0.f;
    for (int i = 0; i < 4; i++) { a += red[i * 2]; b += red[i * 2 + 1]; }
    red[0] = a; red[1] = b;
  }
  __syncthreads();
  s = red[0]; ss = red[1];
}

// ---------------- LN vit: [18432][1024] f32 -> bf16 ----------------
__global__ __launch_bounds__(256) void ln_vit_kernel(
    const float* __restrict__ x, const float* __restrict__ w,
    const float* __restrict__ b, unsigned short* __restrict__ out) {
  __shared__ float red[8];
  const int row = blockIdx.x;
  const int t = threadIdx.x;
  const float4 v = ((const float4*)(x + (size_t)row * 1024))[t];
  float s = v.x + v.y + v.z + v.w;
  float ss = v.x * v.x + v.y * v.y + v.z * v.z + v.w * v.w;
  block_reduce2(s, ss, red);
  const float m = s * (1.f / 1024.f);
  const float var = ss * (1.f / 1024.f) - m * m;
  const float rstd = rsqrtf(var + 1e-5f);
  const float4 w4 = ((const float4*)w)[t];
  const float4 b4 = ((const float4*)b)[t];
  ushort4 o;
  o.x = f2bf((v.x - m) * rstd * w4.x + b4.x);
  o.y = f2bf((v.y - m) * rstd * w4.y + b4.y);
  o.z = f2bf((v.z - m) * rstd * w4.z + b4.z);
  o.w = f2bf((v.w - m) * rstd * w4.w + b4.w);
  ((ushort4*)(out + (size_t)row * 1024))[t] = o;
}

// ---------------- LN box: [3200][1536] f32 -> two bf16 outputs ----------------
__global__ __launch_bounds__(256) void ln_box_kernel(
    const float* __restrict__ x,
    const float* __restrict__ kw, const float* __restrict__ kb,
    const float* __restrict__ vw, const float* __restrict__ vb,
    unsigned short* __restrict__ kn, unsigned short* __restrict__ vn) {
  __shared__ float red[8];
  const int row = blockIdx.x;
  const int t = threadIdx.x;
  const float4* xr = (const float4*)(x + (size_t)row * 1536);
  const float4 a = xr[t];
  float4 c = make_float4(0.f, 0.f, 0.f, 0.f);
  if (t < 128) c = xr[256 + t];
  float s = a.x + a.y + a.z + a.w + c.x + c.y + c.z + c.w;
  float ss = a.x * a.x + a.y * a.y + a.z * a.z + a.w * a.w +
             c.x * c.x + c.y * c.y + c.z * c.z + c.w * c.w;
  block_reduce2(s, ss, red);
  const float m = s * (1.f / 1536.f);
  const float var = ss * (1.f / 1536.f) - m * m;
  const float rstd = rsqrtf(var + 1e-5f);
  {
    const float4 w4 = ((const float4*)kw)[t];
    const float4 b4 = ((const float4*)kb)[t];
    ushort4 o;
    o.x = f2bf((a.x - m) * rstd * w4.x + b4.x);
    o.y = f2bf((a.y - m) * rstd * w4.y + b4.y);
    o.z = f2bf((a.z - m) * rstd * w4.z + b4.z);
    o.w = f2bf((a.w - m) * rstd * w4.w + b4.w);
    ((ushort4*)(kn + (size_t)row * 1536))[t] = o;
    const float4 w4v = ((const float4*)vw)[t];
    const float4 b4v = ((const float4*)vb)[t];
    o.x = f2bf((a.x - m) * rstd * w4v.x + b4v.x);
    o.y = f2bf((a.y - m) * rstd * w4v.y + b4v.y);
    o.z = f2bf((a.z - m) * rstd * w4v.z + b4v.z);
    o.w = f2bf((a.w - m) * rstd * w4v.w + b4v.w);
    ((ushort4*)(vn + (size_t)row * 1536))[t] = o;
  }
  if (t < 128) {
    const int t2 = 256 + t;
    const float4 w4 = ((const float4*)kw)[t2];
    const float4 b4 = ((const float4*)kb)[t2];
    ushort4 o;
    o.x = f2bf((c.x - m) * rstd * w4.x + b4.x);
    o.y = f2bf((c.y - m) * rstd * w4.y + b4.y);
    o.z = f2bf((c.z - m) * rstd * w4.z + b4.z);
    o.w = f2bf((c.w - m) * rstd * w4.w + b4.w);
    ((ushort4*)(kn + (size_t)row * 1536))[t2] = o;
    const float4 w4v = ((const float4*)vw)[t2];
    const float4 b4v = ((const float4*)vb)[t2];
    o.x = f2bf((c.x - m) * rstd * w4v.x + b4v.x);
    o.y = f2bf((c.y - m) * rstd * w4v.y + b4v.y);
    o.z = f2bf((c.z - m) * rstd * w4v.z + b4v.z);
    o.w = f2bf((c.w - m) * rstd * w4v.w + b4v.w);
    ((ushort4*)(vn + (size_t)row * 1536))[t2] = o;
  }
}

// ======== GEMM core, BK=64, double-buffered (T3 minimum 2-phase recipe) ========
// LDS: As,Bs each [2 buf][2 khalf][128][32] bf16 (32 KB each, 64 KB total).
// Iter j: stage tile j+1 -> buf[p^1] (issued BEFORE compute), compute buf[p],
// one __syncthreads (implicit vmcnt0+lgkmcnt0 drain), flip p. Race-free:
// buf[p^1] consumed before previous barrier; staged tile confirmed at this one.
__device__ __forceinline__ void gemm_core_db(
    const unsigned short* __restrict__ A, int lda, int rowmaxA, int tm0,
    const unsigned short* __restrict__ Bt, int ldb, int rowmaxB, int tn0,
    int K, unsigned short* As, unsigned short* Bs, f32x4 acc[4][4]) {
  const int tid = threadIdx.x;
  const int w = tid >> 6, l = tid & 63;
  const int wr = w >> 1, wc = w & 1;
  const int srow = (w << 4) + (l >> 2);
  const int scol = (l & 3) << 3;
  int ra0 = tm0 + srow;      if (ra0 > rowmaxA) ra0 = rowmaxA;
  int ra1 = tm0 + srow + 64; if (ra1 > rowmaxA) ra1 = rowmaxA;
  int rb0 = tn0 + srow;      if (rb0 > rowmaxB) rb0 = rowmaxB;
  int rb1 = tn0 + srow + 64; if (rb1 > rowmaxB) rb1 = rowmaxB;
  const unsigned short* pa0 = A + (size_t)ra0 * lda + scol;
  const unsigned short* pa1 = A + (size_t)ra1 * lda + scol;
  const unsigned short* pb0 = Bt + (size_t)rb0 * ldb + scol;
  const unsigned short* pb1 = Bt + (size_t)rb1 * ldb + scol;
  unsigned short* la0 = As + (w << 4) * 32;
  unsigned short* la1 = As + ((w << 4) + 64) * 32;
  unsigned short* lb0 = Bs + (w << 4) * 32;
  unsigned short* lb1 = Bs + ((w << 4) + 64) * 32;
  const int faoff = (wr << 6) * 32 + ((l & 15) << 5) + ((l >> 4) << 3);
  const int fboff = (wc << 6) * 32 + ((l & 15) << 5) + ((l >> 4) << 3);
#pragma unroll
  for (int i = 0; i < 4; i++)
#pragma unroll
    for (int j = 0; j < 4; j++) acc[i][j] = (f32x4)0.0f;

#define STAGE8(k0, bo) do {                                                  \
    gload16(pa0 + (k0), la0 + (bo));                                         \
    gload16(pa1 + (k0), la1 + (bo));                                         \
    gload16(pb0 + (k0), lb0 + (bo));                                         \
    gload16(pb1 + (k0), lb1 + (bo));                                         \
    gload16(pa0 + (k0) + 32, la0 + (bo) + 4096);                             \
    gload16(pa1 + (k0) + 32, la1 + (bo) + 4096);                             \
    gload16(pb0 + (k0) + 32, lb0 + (bo) + 4096);                             \
    gload16(pb1 + (k0) + 32, lb1 + (bo) + 4096);                             \
  } while (0)

  STAGE8(0, 0);
  __syncthreads();
  int p = 0;
  for (int k0 = 0; k0 < K; k0 += 64) {
    if (k0 + 64 < K) STAGE8(k0 + 64, (p ^ 1) * 8192);
    const unsigned short* fa = As + p * 8192 + faoff;
    const unsigned short* fb = Bs + p * 8192 + fboff;
    {
      short8 a[4], b[4];
#pragma unroll
      for (int i = 0; i < 4; i++) a[i] = *(const short8*)(fa + i * 512);
#pragma unroll
      for (int j = 0; j < 4; j++) b[j] = *(const short8*)(fb + j * 512);
#pragma unroll
      for (int i = 0; i < 4; i++)
#pragma unroll
        for (int j = 0; j < 4; j++)
          acc[i][j] = __builtin_amdgcn_mfma_f32_16x16x32_bf16(a[i], b[j], acc[i][j], 0, 0, 0);
    }
    {
      short8 a[4], b[4];
#pragma unroll
      for (int i = 0; i < 4; i++) a[i] = *(const short8*)(fa + 4096 + i * 512);
#pragma unroll
      for (int j = 0; j < 4; j++) b[j] = *(const short8*)(fb + 4096 + j * 512);
#pragma unroll
      for (int i = 0; i < 4; i++)
#pragma unroll
        for (int j = 0; j < 4; j++)
          acc[i][j] = __builtin_amdgcn_mfma_f32_16x16x32_bf16(a[i], b[j], acc[i][j], 0, 0, 0);
    }
    __syncthreads();
    p ^= 1;
  }
#undef STAGE8
}

// ---------------- Q projection GEMM: bf16 out (+bias) ----------------
__global__ __launch_bounds__(256, 4) void gemm_qkv_kernel(
    const unsigned short* __restrict__ A, const unsigned short* __restrict__ Bt,
    const float* __restrict__ bias, unsigned short* __restrict__ C,
    int M, int N, int K) {
  extern __shared__ unsigned short lds[];
  unsigned short* As = lds;            // [2][8192]
  unsigned short* Bs = lds + 16384;    // [2][8192]
  const int tm0 = blockIdx.x * 128, tn0 = blockIdx.y * 128;
  f32x4 acc[4][4];
  gemm_core_db(A, K, M - 1, tm0, Bt, K, N - 1, tn0, K, As, Bs, acc);
  const int tid = threadIdx.x;
  const int w = tid >> 6, l = tid & 63;
  const int wr = w >> 1, wc = w & 1;
#pragma unroll
  for (int i = 0; i < 4; i++) {
    const int row0 = tm0 + wr * 64 + i * 16 + (l >> 4) * 4;
#pragma unroll
    for (int j = 0; j < 4; j++) {
      const int col = tn0 + wc * 64 + j * 16 + (l & 15);
      const float bv = bias[col];
#pragma unroll
      for (int r = 0; r < 4; r++) {
        const int row = row0 + r;
        if (row < M) C[(size_t)row * N + col] = f2bf(acc[i][j][r] + bv);
      }
    }
  }
}

// ---------------- K+V projections in one grid (z selects) ----------------
__global__ __launch_bounds__(256) void gemm_kv_kernel(
    const unsigned short* __restrict__ kn, const unsigned short* __restrict__ vn,
    const unsigned short* __restrict__ kwt, const unsigned short* __restrict__ vwt,
    const float* __restrict__ kb, const float* __restrict__ vb, float kscale,
    unsigned short* __restrict__ kk, unsigned short* __restrict__ vT) {
  extern __shared__ unsigned short lds[];
  unsigned short* As = lds;
  unsigned short* Bs = lds + 16384;
  const int z = blockIdx.z;
  const unsigned short* A = z ? vn : kn;
  const unsigned short* Bt = z ? vwt : kwt;
  const float* bias = z ? vb : kb;
  const float bscale = z ? 1.0f : kscale;
  const int M = 3200, N = 1024, K = 1536;
  const int tm0 = blockIdx.x * 128, tn0 = blockIdx.y * 128;
  f32x4 acc[4][4];
  gemm_core_db(A, K, M - 1, tm0, Bt, K, N - 1, tn0, K, As, Bs, acc);
  const int tid = threadIdx.x;
  const int w = tid >> 6, l = tid & 63;
  const int wr = w >> 1, wc = w & 1;
#pragma unroll
  for (int i = 0; i < 4; i++) {
    const int row0 = tm0 + wr * 64 + i * 16 + (l >> 4) * 4;
#pragma unroll
    for (int j = 0; j < 4; j++) {
      const int col = tn0 + wc * 64 + j * 16 + (l & 15);
      const float bv = bias[col] * bscale;
#pragma unroll
      for (int r = 0; r < 4; r++) {
        const int row = row0 + r;
        const float val = acc[i][j][r] + bv;
        if (!z) {
          kk[(size_t)row * N + col] = f2bf(val);
        } else {
          const int bb = row / 100;
          const int ll = row - bb * 100;
          vT[((size_t)bb * N + col) * 128 + ll] = f2bf(val);
        }
      }
    }
  }
}

// ---------------- ATT1: 64-row q-tiles; dbuf BK=64 QK^T + masked softmax -> bf16 ----
__global__ __launch_bounds__(256) void att1_kernel(
    const unsigned short* __restrict__ q, const unsigned short* __restrict__ kk,
    const int* __restrict__ lengths, unsigned short* __restrict__ att) {
  __shared__ __align__(16) char smem[49408];
  unsigned short* As = (unsigned short*)smem;            // [2 buf][2 kh][64][32] (16 KB)
  unsigned short* Bs = (unsigned short*)(smem + 16384);  // [2 buf][2 kh][128][32] (32 KB)
  float* Smat = (float*)smem;                            // [128 cols][68] f32 (aliases)
  float* invr = (float*)(smem + 34816);                  // [64] (aliases dead staging)
  const int b = blockIdx.y;
  const int tm0 = blockIdx.x * 64;
  const int t = threadIdx.x;
  const int w = t >> 6, l = t & 63;
  const unsigned short* A = q + (size_t)b * 576 * 1024;
  const unsigned short* B = kk + (size_t)b * 100 * 1024;
  const int sr = t >> 2;
  const int sc8 = (t & 3) << 3;
  const unsigned short* pa = A + (size_t)(tm0 + sr) * 1024 + sc8;
  const unsigned short* pb0 = B + (size_t)sr * 1024 + sc8;
  int rb1 = 64 + sr; if (rb1 > 99) rb1 = 99;
  const unsigned short* pb1 = B + (size_t)rb1 * 1024 + sc8;
  unsigned short* la = As + (w << 9);
  unsigned short* lb0 = Bs + (w << 9);
  unsigned short* lb1 = Bs + 2048 + (w << 9);
  const int foff = ((l & 15) << 5) + ((l >> 4) << 3);

  f32x4 acc[4][2];
#pragma unroll
  for (int i = 0; i < 4; i++) { acc[i][0] = (f32x4)0.0f; acc[i][1] = (f32x4)0.0f; }

#define STG6(k0, bp) do {                                                    \
    gload16(pa + (k0), la + (bp) * 4096);                                    \
    gload16(pb0 + (k0), lb0 + (bp) * 8192);                                  \
    gload16(pb1 + (k0), lb1 + (bp) * 8192);                                  \
    gload16(pa + (k0) + 32, la + (bp) * 4096 + 2048);                        \
    gload16(pb0 + (k0) + 32, lb0 + (bp) * 8192 + 4096);                      \
    gload16(pb1 + (k0) + 32, lb1 + (bp) * 8192 + 4096);                      \
  } while (0)

  STG6(0, 0);
  __syncthreads();
  int p = 0;
  for (int k0 = 0; k0 < 1024; k0 += 64) {
    if (k0 < 960) STG6(k0 + 64, p ^ 1);
    const unsigned short* fa = As + p * 4096 + foff;
    const unsigned short* fb = Bs + p * 8192 + (w << 5) * 32 + foff;
    {
      short8 a[4], bf[2];
#pragma unroll
      for (int i = 0; i < 4; i++) a[i] = *(const short8*)(fa + i * 512);
#pragma unroll
      for (int j = 0; j < 2; j++) bf[j] = *(const short8*)(fb + j * 512);
#pragma unroll
      for (int i = 0; i < 4; i++)
#pragma unroll
        for (int j = 0; j < 2; j++)
          acc[i][j] = __builtin_amdgcn_mfma_f32_16x16x32_bf16(a[i], bf[j], acc[i][j], 0, 0, 0);
    }
    {
      short8 a[4], bf[2];
#pragma unroll
      for (int i = 0; i < 4; i++) a[i] = *(const short8*)(fa + 2048 + i * 512);
#pragma unroll
      for (int j = 0; j < 2; j++) bf[j] = *(const short8*)(fb + 4096 + j * 512);
#pragma unroll
      for (int i = 0; i < 4; i++)
#pragma unroll
        for (int j = 0; j < 2; j++)
          acc[i][j] = __builtin_amdgcn_mfma_f32_16x16x32_bf16(a[i], bf[j], acc[i][j], 0, 0, 0);
    }
    __syncthreads();
    p ^= 1;
  }
#undef STG6

  // store S col-major: Smat[c][r], stride 68
#pragma unroll
  for (int i = 0; i < 4; i++) {
    const int r0 = i * 16 + (l >> 4) * 4;
#pragma unroll
    for (int j = 0; j < 2; j++) {
      const int c = (w << 5) + j * 16 + (l & 15);
#pragma unroll
      for (int rr = 0; rr < 4; rr++) Smat[c * 68 + r0 + rr] = acc[i][j][rr];
    }
  }
  __syncthreads();

  // softmax: 4 lanes per row; lane g handles cols g*25..g*25+24
  const int r = t >> 2, g = t & 3;
  const int len = lengths[b];
  float mx = NEG_FLT_MAX;
#pragma unroll
  for (int i = 0; i < 25; i++) {
    const int ll = g * 25 + i;
    const float v = (ll < len) ? Smat[ll * 68 + r] : NEG_FLT_MAX;
    mx = fmaxf(mx, v);
  }
  mx = fmaxf(mx, __shfl_xor(mx, 1));
  mx = fmaxf(mx, __shfl_xor(mx, 2));
  float sum = 0.f;
#pragma unroll
  for (int i = 0; i < 25; i++) {
    const int ll = g * 25 + i;
    const float v = (ll < len) ? Smat[ll * 68 + r] : NEG_FLT_MAX;
    const float e = __expf(v - mx);
    Smat[ll * 68 + r] = e;
    sum += e;
  }
  sum += __shfl_xor(sum, 1);
  sum += __shfl_xor(sum, 2);
  if (g == 0) invr[r] = 1.f / sum;
  __syncthreads();

  const float inv = invr[r];
  unsigned short* arow = att + ((size_t)b * 576 + tm0 + r) * 128;
#pragma unroll
  for (int j = 0; j < 8; j++) {
    const int c0 = g * 32 + j * 4;
    ushort4 o;
    o.x = (c0 + 0 < 100) ? f2bf(Smat[(c0 + 0) * 68 + r] * inv) : (unsigned short)0;
    o.y = (c0 + 1 < 100) ? f2bf(Smat[(c0 + 1) * 68 + r] * inv) : (unsigned short)0;
    o.z = (c0 + 2 < 100) ? f2bf(Smat[(c0 + 2) * 68 + r] * inv) : (unsigned short)0;
    o.w = (c0 + 3 < 100) ? f2bf(Smat[(c0 + 3) * 68 + r] * inv) : (unsigned short)0;
    ((ushort4*)arow)[g * 8 + j] = o;
  }
}

// ---------------- ATT2: out = att @ v + vit (fp32 out) ----------------
__global__ __launch_bounds__(256) void att2_kernel(
    const unsigned short* __restrict__ att, const unsigned short* __restrict__ vT,
    const float* __restrict__ vit, float* __restrict__ out) {
  extern __shared__ unsigned short lds[];
  unsigned short* As = lds;
  unsigned short* Bs = lds + 16384;
  const int b = blockIdx.z;
  const int tm0 = blockIdx.x * 128, tn0 = blockIdx.y * 128;
  f32x4 acc[4][4];
  gemm_core_db(att + (size_t)b * 576 * 128, 128, 575, tm0,
               vT + (size_t)b * 1024 * 128, 128, 1023, tn0, 128, As, Bs, acc);
  const int tid = threadIdx.x;
  const int w = tid >> 6, l = tid & 63;
  const int wr = w >> 1, wc = w & 1;
#pragma unroll
  for (int i = 0; i < 4; i++) {
    const int row0 = tm0 + wr * 64 + i * 16 + (l >> 4) * 4;
#pragma unroll
    for (int j = 0; j < 4; j++) {
      const int col = tn0 + wc * 64 + j * 16 + (l & 15);
#pragma unroll
      for (int r = 0; r < 4; r++) {
        const int row = row0 + r;
        if (row < 576) {
          const size_t idx = ((size_t)b * 576 + row) * 1024 + col;
          out[idx] = acc[i][j][r] + vit[idx];
        }
      }
    }
  }
}

extern "C" void kernel_launch(void* const* d_in, const int* in_sizes, int n_in,
                              void* d_out, int out_size, void* d_ws, size_t ws_size,
                              hipStream_t stream) {
  const float* vit = (const float*)d_in[0];
  const float* box = (const float*)d_in[1];
  const int* lengths = (const int*)d_in[2];
  const float* q_ln_w = (const float*)d_in[3];
  const float* q_ln_b = (const float*)d_in[4];
  const float* q_w = (const float*)d_in[5];
  const float* q_b = (const float*)d_in[6];
  const float* k_ln_w = (const float*)d_in[7];
  const float* k_ln_b = (const float*)d_in[8];
  const float* k_w = (const float*)d_in[9];
  const float* k_b = (const float*)d_in[10];
  const float* v_ln_w = (const float*)d_in[11];
  const float* v_ln_b = (const float*)d_in[12];
  const float* v_w = (const float*)d_in[13];
  const float* v_b = (const float*)d_in[14];
  float* out = (float*)d_out;
  char* ws = (char*)d_ws;

  unsigned short* q    = (unsigned short*)(ws + 0);          // [18432][1024] bf16
  unsigned short* kn   = (unsigned short*)(ws + 0);          // [3200][1536]
  unsigned short* vn   = (unsigned short*)(ws + 9830400);    // [3200][1536]
  unsigned short* k_wt = (unsigned short*)(ws + 37748736);   // [1024][1536]
  unsigned short* v_wt = (unsigned short*)(ws + 40894464);   // [1024][1536]
  unsigned short* q_wt = (unsigned short*)(ws + 44040192);   // [1024][1024]
  unsigned short* kk   = (unsigned short*)(ws + 46137344);   // [3200][1024]
  unsigned short* vT   = (unsigned short*)(ws + 52690944);   // [32][1024][128]
  unsigned short* att  = (unsigned short*)(ws + 61079552);   // [32][576][128]
  unsigned short* qn   = (unsigned short*)d_out;             // bf16 scratch in output buf

  const float scale = 0.03125f;  // 1/sqrt(1024)

  // allow 64 KiB dynamic LDS for the dbuf GEMM kernels
  (void)hipFuncSetAttribute((const void*)gemm_qkv_kernel,
                            hipFuncAttributeMaxDynamicSharedMemorySize, 65536);
  (void)hipFuncSetAttribute((const void*)gemm_kv_kernel,
                            hipFuncAttributeMaxDynamicSharedMemorySize, 65536);
  (void)hipFuncSetAttribute((const void*)att2_kernel,
                            hipFuncAttributeMaxDynamicSharedMemorySize, 65536);

  // 1. merged weight transposes (+fold scale into k)
  tp3_kernel<<<dim3(32, 48, 3), dim3(32, 8), 0, stream>>>(
      q_w, k_w, v_w, q_wt, k_wt, v_wt, scale);

  // 2. LN box (shared stats, two outputs)
  ln_box_kernel<<<3200, 256, 0, stream>>>(box, k_ln_w, k_ln_b, v_ln_w, v_ln_b, kn, vn);

  // 3. K and V projections, one grid (V written transposed to [B][1024][128])
  gemm_kv_kernel<<<dim3(25, 8, 2), 256, 65536, stream>>>(
      kn, vn, k_wt, v_wt, k_b, v_b, scale, kk, vT);

  // 4. LN vit -> qn (scratch in d_out)
  ln_vit_kernel<<<18432, 256, 0, stream>>>(vit, q_ln_w, q_ln_b, qn);

  // 5. Q projection (dbuf BK=64)
  gemm_qkv_kernel<<<dim3(144, 8), 256, 65536, stream>>>(qn, q_wt, q_b, q, 18432, 1024, 1024);

  // 6. attention scores + masked softmax -> bf16 att [B][576][128]
  att1_kernel<<<dim3(9, 32), 256, 0, stream>>>(q, kk, lengths, att);

  // 7. out = att @ v + vit
  att2_kernel<<<dim3(5, 8, 32), 256, 65536, stream>>>(att, vT, vit, out);

  (void)in_sizes; (void)n_in; (void)out_size; (void)ws_size;
}

// Round 7
// 186.448 us; speedup vs baseline: 1.2671x; 1.2671x over previous
//
#include <hip/hip_runtime.h>
#include <stdint.h>

typedef __attribute__((ext_vector_type(8))) short short8;
typedef __attribute__((ext_vector_type(4))) float f32x4;

#define NEG_FLT_MAX (-3.402823466e38f)

__device__ __forceinline__ unsigned short f2bf(float f) {
  uint32_t u = __float_as_uint(f);
  uint32_t r = (u + 0x7fffu + ((u >> 16) & 1u)) >> 16;
  return (unsigned short)r;
}

__device__ __forceinline__ float bf2f(unsigned short u) {
  return __uint_as_float(((uint32_t)u) << 16);
}

__device__ __forceinline__ void gload16(const void* g, void* l) {
  __builtin_amdgcn_global_load_lds(
      (const __attribute__((address_space(1))) uint32_t*)g,
      (__attribute__((address_space(3))) uint32_t*)l, 16, 0, 0);
}

// ---------------- V weight transpose: [1536][1024] f32 -> [1024][1536] bf16 ----------
__global__ void tpv_kernel(const float* __restrict__ src, unsigned short* __restrict__ dst) {
  __shared__ float tile[32][33];
  const int c0 = blockIdx.x * 32;  // col in src (0..1023)
  const int r0 = blockIdx.y * 32;  // row in src (0..1535)
  const int tx = threadIdx.x, ty = threadIdx.y;  // 32 x 8
#pragma unroll
  for (int i = ty; i < 32; i += 8)
    tile[i][tx] = src[(size_t)(r0 + i) * 1024 + (c0 + tx)];
  __syncthreads();
#pragma unroll
  for (int i = ty; i < 32; i += 8)
    dst[(size_t)(c0 + i) * 1536 + (r0 + tx)] = f2bf(tile[tx][i]);
}

// ---------------- weight converts: q_w -> bf16 (native), k_w*scale -> bf16 (native) ----
__global__ __launch_bounds__(256) void wconv_kernel(
    const float* __restrict__ qw, const float* __restrict__ kw,
    unsigned short* __restrict__ qwb, unsigned short* __restrict__ kwb, float scale) {
  const int idx = blockIdx.x * 256 + threadIdx.x;  // group of 4 elems
  const int QG = 1024 * 1024 / 4;
  if (idx < QG) {
    float4 v = ((const float4*)qw)[idx];
    ushort4 o;
    o.x = f2bf(v.x); o.y = f2bf(v.y); o.z = f2bf(v.z); o.w = f2bf(v.w);
    ((ushort4*)qwb)[idx] = o;
  } else {
    const int j = idx - QG;  // < 1536*1024/4
    float4 v = ((const float4*)kw)[j];
    ushort4 o;
    o.x = f2bf(v.x * scale); o.y = f2bf(v.y * scale);
    o.z = f2bf(v.z * scale); o.w = f2bf(v.w * scale);
    ((ushort4*)kwb)[j] = o;
  }
}

// ---------------- small weight vectors: bias3[i]=qw[i,:]·kb*s, w4[j]=kw[j,:]·qb*s, c4=qb·kb*s
__global__ __launch_bounds__(256) void wvec_kernel(
    const float* __restrict__ qw, const float* __restrict__ kw,
    const float* __restrict__ qb, const float* __restrict__ kb, float scale,
    float* __restrict__ bias3, float* __restrict__ w4, float* __restrict__ c4) {
  const int wv = threadIdx.x >> 6, l = threadIdx.x & 63;
  const int idx = blockIdx.x;
  float s = 0.f;
  if (idx < 256) {
    const int i = idx * 4 + wv;
    const float* row = qw + (size_t)i * 1024;
#pragma unroll
    for (int s0 = 0; s0 < 1024; s0 += 256) {
      float4 a = *(const float4*)(row + s0 + l * 4);
      float4 b = *(const float4*)(kb + s0 + l * 4);
      s += a.x * b.x + a.y * b.y + a.z * b.z + a.w * b.w;
    }
#pragma unroll
    for (int off = 32; off; off >>= 1) s += __shfl_xor(s, off);
    if (l == 0) bias3[i] = s * scale;
  } else if (idx < 640) {
    const int j = (idx - 256) * 4 + wv;
    const float* row = kw + (size_t)j * 1024;
#pragma unroll
    for (int s0 = 0; s0 < 1024; s0 += 256) {
      float4 a = *(const float4*)(row + s0 + l * 4);
      float4 b = *(const float4*)(qb + s0 + l * 4);
      s += a.x * b.x + a.y * b.y + a.z * b.z + a.w * b.w;
    }
#pragma unroll
    for (int off = 32; off; off >>= 1) s += __shfl_xor(s, off);
    if (l == 0) w4[j] = s * scale;
  } else if (wv == 0) {
#pragma unroll
    for (int s0 = 0; s0 < 1024; s0 += 256) {
      float4 a = *(const float4*)(qb + s0 + l * 4);
      float4 b = *(const float4*)(kb + s0 + l * 4);
      s += a.x * b.x + a.y * b.y + a.z * b.z + a.w * b.w;
    }
#pragma unroll
    for (int off = 32; off; off >>= 1) s += __shfl_xor(s, off);
    if (l == 0) *c4 = s * scale;
  }
}

// ---------------- block reduction helper ----------------
__device__ __forceinline__ void block_reduce2(float& s, float& ss, float* red) {
#pragma unroll
  for (int off = 32; off > 0; off >>= 1) {
    s += __shfl_xor(s, off);
    ss += __shfl_xor(ss, off);
  }
  const int wave = threadIdx.x >> 6;
  const int lane = threadIdx.x & 63;
  if (lane == 0) { red[wave * 2] = s; red[wave * 2 + 1] = ss; }
  __syncthreads();
  if (threadIdx.x == 0) {
    float a = 0.f, b = 0.f;
    for (int i = 0; i < 4; i++) { a += red[i * 2]; b += red[i * 2 + 1]; }
    red[0] = a; red[1] = b;
  }
  __syncthreads();
  s = red[0]; ss = red[1];
}

// ---------------- LN vit: [18432][1024] f32 -> bf16 ----------------
__global__ __launch_bounds__(256) void ln_vit_kernel(
    const float* __restrict__ x, const float* __restrict__ w,
    const float* __restrict__ b, unsigned short* __restrict__ out) {
  __shared__ float red[8];
  const int row = blockIdx.x;
  const int t = threadIdx.x;
  const float4 v = ((const float4*)(x + (size_t)row * 1024))[t];
  float s = v.x + v.y + v.z + v.w;
  float ss = v.x * v.x + v.y * v.y + v.z * v.z + v.w * v.w;
  block_reduce2(s, ss, red);
  const float m = s * (1.f / 1024.f);
  const float var = ss * (1.f / 1024.f) - m * m;
  const float rstd = rsqrtf(var + 1e-5f);
  const float4 w4 = ((const float4*)w)[t];
  const float4 b4 = ((const float4*)b)[t];
  ushort4 o;
  o.x = f2bf((v.x - m) * rstd * w4.x + b4.x);
  o.y = f2bf((v.y - m) * rstd * w4.y + b4.y);
  o.z = f2bf((v.z - m) * rstd * w4.z + b4.z);
  o.w = f2bf((v.w - m) * rstd * w4.w + b4.w);
  ((ushort4*)(out + (size_t)row * 1024))[t] = o;
}

// ---------------- LN box: [3200][1536] f32 -> two bf16 outputs ----------------
__global__ __launch_bounds__(256) void ln_box_kernel(
    const float* __restrict__ x,
    const float* __restrict__ kw, const float* __restrict__ kb,
    const float* __restrict__ vw, const float* __restrict__ vb,
    unsigned short* __restrict__ kn, unsigned short* __restrict__ vn) {
  __shared__ float red[8];
  const int row = blockIdx.x;
  const int t = threadIdx.x;
  const float4* xr = (const float4*)(x + (size_t)row * 1536);
  const float4 a = xr[t];
  float4 c = make_float4(0.f, 0.f, 0.f, 0.f);
  if (t < 128) c = xr[256 + t];
  float s = a.x + a.y + a.z + a.w + c.x + c.y + c.z + c.w;
  float ss = a.x * a.x + a.y * a.y + a.z * a.z + a.w * a.w +
             c.x * c.x + c.y * c.y + c.z * c.z + c.w * c.w;
  block_reduce2(s, ss, red);
  const float m = s * (1.f / 1536.f);
  const float var = ss * (1.f / 1536.f) - m * m;
  const float rstd = rsqrtf(var + 1e-5f);
  {
    const float4 w4 = ((const float4*)kw)[t];
    const float4 b4 = ((const float4*)kb)[t];
    ushort4 o;
    o.x = f2bf((a.x - m) * rstd * w4.x + b4.x);
    o.y = f2bf((a.y - m) * rstd * w4.y + b4.y);
    o.z = f2bf((a.z - m) * rstd * w4.z + b4.z);
    o.w = f2bf((a.w - m) * rstd * w4.w + b4.w);
    ((ushort4*)(kn + (size_t)row * 1536))[t] = o;
    const float4 w4v = ((const float4*)vw)[t];
    const float4 b4v = ((const float4*)vb)[t];
    o.x = f2bf((a.x - m) * rstd * w4v.x + b4v.x);
    o.y = f2bf((a.y - m) * rstd * w4v.y + b4v.y);
    o.z = f2bf((a.z - m) * rstd * w4v.z + b4v.z);
    o.w = f2bf((a.w - m) * rstd * w4v.w + b4v.w);
    ((ushort4*)(vn + (size_t)row * 1536))[t] = o;
  }
  if (t < 128) {
    const int t2 = 256 + t;
    const float4 w4 = ((const float4*)kw)[t2];
    const float4 b4 = ((const float4*)kb)[t2];
    ushort4 o;
    o.x = f2bf((c.x - m) * rstd * w4.x + b4.x);
    o.y = f2bf((c.y - m) * rstd * w4.y + b4.y);
    o.z = f2bf((c.z - m) * rstd * w4.z + b4.z);
    o.w = f2bf((c.w - m) * rstd * w4.w + b4.w);
    ((ushort4*)(kn + (size_t)row * 1536))[t2] = o;
    const float4 w4v = ((const float4*)vw)[t2];
    const float4 b4v = ((const float4*)vb)[t2];
    o.x = f2bf((c.x - m) * rstd * w4v.x + b4v.x);
    o.y = f2bf((c.y - m) * rstd * w4v.y + b4v.y);
    o.z = f2bf((c.z - m) * rstd * w4v.z + b4v.z);
    o.w = f2bf((c.w - m) * rstd * w4v.w + b4v.w);
    ((ushort4*)(vn + (size_t)row * 1536))[t2] = o;
  }
}

// ---------------- qbk[row] = kn[row,:]·w4 + c4, row < 3200 ----------------
__global__ __launch_bounds__(256) void qbk_kernel(
    const unsigned short* __restrict__ kn, const float* __restrict__ w4,
    const float* __restrict__ c4, float* __restrict__ qbk) {
  const int wv = threadIdx.x >> 6, l = threadIdx.x & 63;
  const int row = blockIdx.x * 4 + wv;
  const unsigned short* r = kn + (size_t)row * 1536;
  float s = 0.f;
#pragma unroll
  for (int s0 = 0; s0 < 1536; s0 += 512) {
    short8 v = *(const short8*)(r + s0 + l * 8);
    const float* wp = w4 + s0 + l * 8;
    float4 w0 = *(const float4*)wp;
    float4 w1 = *(const float4*)(wp + 4);
    s += bf2f((unsigned short)v[0]) * w0.x + bf2f((unsigned short)v[1]) * w0.y +
         bf2f((unsigned short)v[2]) * w0.z + bf2f((unsigned short)v[3]) * w0.w +
         bf2f((unsigned short)v[4]) * w1.x + bf2f((unsigned short)v[5]) * w1.y +
         bf2f((unsigned short)v[6]) * w1.z + bf2f((unsigned short)v[7]) * w1.w;
  }
#pragma unroll
  for (int off = 32; off; off >>= 1) s += __shfl_xor(s, off);
  if (l == 0) qbk[row] = s + *c4;
}

// ---------------- GEMM core, BK=64 (proven r5 structure) ----------
__device__ __forceinline__ void gemm_core64(
    const unsigned short* __restrict__ A, int lda, int rowmaxA, int tm0,
    const unsigned short* __restrict__ Bt, int ldb, int rowmaxB, int tn0,
    int K, unsigned short* As, unsigned short* Bs, f32x4 acc[4][4]) {
  const int tid = threadIdx.x;
  const int w = tid >> 6, l = tid & 63;
  const int wr = w >> 1, wc = w & 1;
  const int srow = (w << 4) + (l >> 2);
  const int scol = (l & 3) << 3;
  int ra0 = tm0 + srow;      if (ra0 > rowmaxA) ra0 = rowmaxA;
  int ra1 = tm0 + srow + 64; if (ra1 > rowmaxA) ra1 = rowmaxA;
  int rb0 = tn0 + srow;      if (rb0 > rowmaxB) rb0 = rowmaxB;
  int rb1 = tn0 + srow + 64; if (rb1 > rowmaxB) rb1 = rowmaxB;
  const unsigned short* pa0 = A + (size_t)ra0 * lda + scol;
  const unsigned short* pa1 = A + (size_t)ra1 * lda + scol;
  const unsigned short* pb0 = Bt + (size_t)rb0 * ldb + scol;
  const unsigned short* pb1 = Bt + (size_t)rb1 * ldb + scol;
  unsigned short* la0 = As + (w << 4) * 32;
  unsigned short* la1 = As + ((w << 4) + 64) * 32;
  unsigned short* lb0 = Bs + (w << 4) * 32;
  unsigned short* lb1 = Bs + ((w << 4) + 64) * 32;
  const int foff = ((l & 15) << 5) + ((l >> 4) << 3);
  const unsigned short* fa = As + (wr << 6) * 32 + foff;
  const unsigned short* fb = Bs + (wc << 6) * 32 + foff;
#pragma unroll
  for (int i = 0; i < 4; i++)
#pragma unroll
    for (int j = 0; j < 4; j++) acc[i][j] = (f32x4)0.0f;
  for (int k0 = 0; k0 < K; k0 += 64) {
    gload16(pa0 + k0, la0);
    gload16(pa1 + k0, la1);
    gload16(pb0 + k0, lb0);
    gload16(pb1 + k0, lb1);
    gload16(pa0 + k0 + 32, la0 + 4096);
    gload16(pa1 + k0 + 32, la1 + 4096);
    gload16(pb0 + k0 + 32, lb0 + 4096);
    gload16(pb1 + k0 + 32, lb1 + 4096);
    __syncthreads();
    {
      short8 a[4], b[4];
#pragma unroll
      for (int i = 0; i < 4; i++) a[i] = *(const short8*)(fa + i * 512);
#pragma unroll
      for (int j = 0; j < 4; j++) b[j] = *(const short8*)(fb + j * 512);
#pragma unroll
      for (int i = 0; i < 4; i++)
#pragma unroll
        for (int j = 0; j < 4; j++)
          acc[i][j] = __builtin_amdgcn_mfma_f32_16x16x32_bf16(a[i], b[j], acc[i][j], 0, 0, 0);
    }
    {
      short8 a[4], b[4];
#pragma unroll
      for (int i = 0; i < 4; i++) a[i] = *(const short8*)(fa + 4096 + i * 512);
#pragma unroll
      for (int j = 0; j < 4; j++) b[j] = *(const short8*)(fb + 4096 + j * 512);
#pragma unroll
      for (int i = 0; i < 4; i++)
#pragma unroll
        for (int j = 0; j < 4; j++)
          acc[i][j] = __builtin_amdgcn_mfma_f32_16x16x32_bf16(a[i], b[j], acc[i][j], 0, 0, 0);
    }
    __syncthreads();
  }
}

// ---------------- W3 = qwb @ kwb^T : [1024][1536] bf16 (scale inside kwb) ----------
__global__ __launch_bounds__(256) void gemm_w3_kernel(
    const unsigned short* __restrict__ qwb, const unsigned short* __restrict__ kwb,
    unsigned short* __restrict__ W3) {
  __shared__ unsigned short As[128 * 64];
  __shared__ unsigned short Bs[128 * 64];
  const int tm0 = blockIdx.x * 128, tn0 = blockIdx.y * 128;
  f32x4 acc[4][4];
  gemm_core64(qwb, 1024, 1023, tm0, kwb, 1024, 1535, tn0, 1024, As, Bs, acc);
  const int tid = threadIdx.x;
  const int w = tid >> 6, l = tid & 63;
  const int wr = w >> 1, wc = w & 1;
#pragma unroll
  for (int i = 0; i < 4; i++) {
    const int row0 = tm0 + wr * 64 + i * 16 + (l >> 4) * 4;
#pragma unroll
    for (int j = 0; j < 4; j++) {
      const int col = tn0 + wc * 64 + j * 16 + (l & 15);
#pragma unroll
      for (int r = 0; r < 4; r++)
        W3[(size_t)(row0 + r) * 1536 + col] = f2bf(acc[i][j][r]);
    }
  }
}

// ---------------- kq + vT projections in one grid (z selects) ----------------
// z=0: kq = kn @ W3^T + bias3   [3200][1024]
// z=1: vT = vn @ v_wt^T + v_b   transposed write [32][1024][128]
__global__ __launch_bounds__(256) void gemm_kv_kernel(
    const unsigned short* __restrict__ kn, const unsigned short* __restrict__ vn,
    const unsigned short* __restrict__ W3, const unsigned short* __restrict__ vwt,
    const float* __restrict__ bias3, const float* __restrict__ vb,
    unsigned short* __restrict__ kq, unsigned short* __restrict__ vT) {
  __shared__ unsigned short As[128 * 64];
  __shared__ unsigned short Bs[128 * 64];
  const int z = blockIdx.z;
  const unsigned short* A = z ? vn : kn;
  const unsigned short* Bt = z ? vwt : W3;
  const float* bias = z ? vb : bias3;
  const int M = 3200, N = 1024, K = 1536;
  const int tm0 = blockIdx.x * 128, tn0 = blockIdx.y * 128;
  f32x4 acc[4][4];
  gemm_core64(A, K, M - 1, tm0, Bt, K, N - 1, tn0, K, As, Bs, acc);
  const int tid = threadIdx.x;
  const int w = tid >> 6, l = tid & 63;
  const int wr = w >> 1, wc = w & 1;
#pragma unroll
  for (int i = 0; i < 4; i++) {
    const int row0 = tm0 + wr * 64 + i * 16 + (l >> 4) * 4;
#pragma unroll
    for (int j = 0; j < 4; j++) {
      const int col = tn0 + wc * 64 + j * 16 + (l & 15);
      const float bv = bias[col];
#pragma unroll
      for (int r = 0; r < 4; r++) {
        const int row = row0 + r;
        const float val = acc[i][j][r] + bv;
        if (!z) {
          kq[(size_t)row * N + col] = f2bf(val);
        } else {
          const int bb = row / 100;
          const int ll = row - bb * 100;
          vT[((size_t)bb * N + col) * 128 + ll] = f2bf(val);
        }
      }
    }
  }
}

// ---------------- ATT1: scores = qn @ kq^T + qbk, mask, softmax -> bf16 att ----
__global__ __launch_bounds__(256) void att1_kernel(
    const unsigned short* __restrict__ qn, const unsigned short* __restrict__ kq,
    const float* __restrict__ qbk, const int* __restrict__ lengths,
    unsigned short* __restrict__ att) {
  __shared__ __align__(16) char smem[35584];
  unsigned short* As = (unsigned short*)smem;            // [2kh][64][32] (8 KB)
  unsigned short* Bs = (unsigned short*)(smem + 8192);   // [2kh][128][32] (16 KB)
  float* Smat = (float*)smem;                            // [128 cols][68] (aliases)
  float* invr = (float*)(smem + 34816);                  // [64]
  float* qb_l = (float*)(smem + 35072);                  // [128]
  const int b = blockIdx.y;
  const int tm0 = blockIdx.x * 64;
  const int t = threadIdx.x;
  const int w = t >> 6, l = t & 63;
  if (t < 128) qb_l[t] = (t < 100) ? qbk[b * 100 + t] : 0.f;
  const unsigned short* A = qn + (size_t)b * 576 * 1024;
  const unsigned short* B = kq + (size_t)b * 100 * 1024;
  const int sr = t >> 2;
  const int sc8 = (t & 3) << 3;
  const unsigned short* pa = A + (size_t)(tm0 + sr) * 1024 + sc8;
  const unsigned short* pb0 = B + (size_t)sr * 1024 + sc8;
  int rb1 = 64 + sr; if (rb1 > 99) rb1 = 99;
  const unsigned short* pb1 = B + (size_t)rb1 * 1024 + sc8;
  unsigned short* la = As + (w << 9);
  unsigned short* lb0 = Bs + (w << 9);
  unsigned short* lb1 = Bs + 2048 + (w << 9);
  const int foff = ((l & 15) << 5) + ((l >> 4) << 3);
  const unsigned short* fa = As + foff;
  const unsigned short* fb = Bs + (w << 5) * 32 + foff;

  f32x4 acc[4][2];
#pragma unroll
  for (int i = 0; i < 4; i++) { acc[i][0] = (f32x4)0.0f; acc[i][1] = (f32x4)0.0f; }

  for (int k0 = 0; k0 < 1024; k0 += 64) {
    gload16(pa + k0, la);
    gload16(pb0 + k0, lb0);
    gload16(pb1 + k0, lb1);
    gload16(pa + k0 + 32, la + 2048);
    gload16(pb0 + k0 + 32, lb0 + 4096);
    gload16(pb1 + k0 + 32, lb1 + 4096);
    __syncthreads();
    {
      short8 a[4], bf[2];
#pragma unroll
      for (int i = 0; i < 4; i++) a[i] = *(const short8*)(fa + i * 512);
#pragma unroll
      for (int j = 0; j < 2; j++) bf[j] = *(const short8*)(fb + j * 512);
#pragma unroll
      for (int i = 0; i < 4; i++)
#pragma unroll
        for (int j = 0; j < 2; j++)
          acc[i][j] = __builtin_amdgcn_mfma_f32_16x16x32_bf16(a[i], bf[j], acc[i][j], 0, 0, 0);
    }
    {
      short8 a[4], bf[2];
#pragma unroll
      for (int i = 0; i < 4; i++) a[i] = *(const short8*)(fa + 2048 + i * 512);
#pragma unroll
      for (int j = 0; j < 2; j++) bf[j] = *(const short8*)(fb + 4096 + j * 512);
#pragma unroll
      for (int i = 0; i < 4; i++)
#pragma unroll
        for (int j = 0; j < 2; j++)
          acc[i][j] = __builtin_amdgcn_mfma_f32_16x16x32_bf16(a[i], bf[j], acc[i][j], 0, 0, 0);
    }
    __syncthreads();
  }

  // store S col-major (+ per-l bias): Smat[c][r], stride 68
#pragma unroll
  for (int i = 0; i < 4; i++) {
    const int r0 = i * 16 + (l >> 4) * 4;
#pragma unroll
    for (int j = 0; j < 2; j++) {
      const int c = (w << 5) + j * 16 + (l & 15);
      const float qb = qb_l[c];
#pragma unroll
      for (int rr = 0; rr < 4; rr++) Smat[c * 68 + r0 + rr] = acc[i][j][rr] + qb;
    }
  }
  __syncthreads();

  // softmax: 4 lanes per row; lane g handles cols g*25..g*25+24
  const int r = t >> 2, g = t & 3;
  const int len = lengths[b];
  float mx = NEG_FLT_MAX;
#pragma unroll
  for (int i = 0; i < 25; i++) {
    const int ll = g * 25 + i;
    const float v = (ll < len) ? Smat[ll * 68 + r] : NEG_FLT_MAX;
    mx = fmaxf(mx, v);
  }
  mx = fmaxf(mx, __shfl_xor(mx, 1));
  mx = fmaxf(mx, __shfl_xor(mx, 2));
  float sum = 0.f;
#pragma unroll
  for (int i = 0; i < 25; i++) {
    const int ll = g * 25 + i;
    const float v = (ll < len) ? Smat[ll * 68 + r] : NEG_FLT_MAX;
    const float e = __expf(v - mx);
    Smat[ll * 68 + r] = e;
    sum += e;
  }
  sum += __shfl_xor(sum, 1);
  sum += __shfl_xor(sum, 2);
  if (g == 0) invr[r] = 1.f / sum;
  __syncthreads();

  const float inv = invr[r];
  unsigned short* arow = att + ((size_t)b * 576 + tm0 + r) * 128;
#pragma unroll
  for (int j = 0; j < 8; j++) {
    const int c0 = g * 32 + j * 4;
    ushort4 o;
    o.x = (c0 + 0 < 100) ? f2bf(Smat[(c0 + 0) * 68 + r] * inv) : (unsigned short)0;
    o.y = (c0 + 1 < 100) ? f2bf(Smat[(c0 + 1) * 68 + r] * inv) : (unsigned short)0;
    o.z = (c0 + 2 < 100) ? f2bf(Smat[(c0 + 2) * 68 + r] * inv) : (unsigned short)0;
    o.w = (c0 + 3 < 100) ? f2bf(Smat[(c0 + 3) * 68 + r] * inv) : (unsigned short)0;
    ((ushort4*)arow)[g * 8 + j] = o;
  }
}

// ---------------- ATT2: out = att @ v + vit (fp32 out) ----------------
__global__ __launch_bounds__(256) void att2_kernel(
    const unsigned short* __restrict__ att, const unsigned short* __restrict__ vT,
    const float* __restrict__ vit, float* __restrict__ out) {
  __shared__ unsigned short As[128 * 64];
  __shared__ unsigned short Bs[128 * 64];
  const int b = blockIdx.z;
  const int tm0 = blockIdx.x * 128, tn0 = blockIdx.y * 128;
  f32x4 acc[4][4];
  gemm_core64(att + (size_t)b * 576 * 128, 128, 575, tm0,
              vT + (size_t)b * 1024 * 128, 128, 1023, tn0, 128, As, Bs, acc);
  const int tid = threadIdx.x;
  const int w = tid >> 6, l = tid & 63;
  const int wr = w >> 1, wc = w & 1;
#pragma unroll
  for (int i = 0; i < 4; i++) {
    const int row0 = tm0 + wr * 64 + i * 16 + (l >> 4) * 4;
#pragma unroll
    for (int j = 0; j < 4; j++) {
      const int col = tn0 + wc * 64 + j * 16 + (l & 15);
#pragma unroll
      for (int r = 0; r < 4; r++) {
        const int row = row0 + r;
        if (row < 576) {
          const size_t idx = ((size_t)b * 576 + row) * 1024 + col;
          out[idx] = acc[i][j][r] + vit[idx];
        }
      }
    }
  }
}

extern "C" void kernel_launch(void* const* d_in, const int* in_sizes, int n_in,
                              void* d_out, int out_size, void* d_ws, size_t ws_size,
                              hipStream_t stream) {
  const float* vit = (const float*)d_in[0];
  const float* box = (const float*)d_in[1];
  const int* lengths = (const int*)d_in[2];
  const float* q_ln_w = (const float*)d_in[3];
  const float* q_ln_b = (const float*)d_in[4];
  const float* q_w = (const float*)d_in[5];
  const float* q_b = (const float*)d_in[6];
  const float* k_ln_w = (const float*)d_in[7];
  const float* k_ln_b = (const float*)d_in[8];
  const float* k_w = (const float*)d_in[9];
  const float* k_b = (const float*)d_in[10];
  const float* v_ln_w = (const float*)d_in[11];
  const float* v_ln_b = (const float*)d_in[12];
  const float* v_w = (const float*)d_in[13];
  const float* v_b = (const float*)d_in[14];
  float* out = (float*)d_out;
  char* ws = (char*)d_ws;

  unsigned short* kn    = (unsigned short*)(ws + 0);          // [3200][1536]
  unsigned short* vn    = (unsigned short*)(ws + 9830400);    // [3200][1536]
  unsigned short* v_wt  = (unsigned short*)(ws + 19660800);   // [1024][1536]
  unsigned short* qwb   = (unsigned short*)(ws + 22806528);   // [1024][1024]
  unsigned short* kwb   = (unsigned short*)(ws + 24903680);   // [1536][1024] (scaled)
  unsigned short* W3    = (unsigned short*)(ws + 28049408);   // [1024][1536]
  float*          bias3 = (float*)(ws + 31195136);            // [1024]
  float*          w4    = (float*)(ws + 31199232);            // [1536]
  float*          c4    = (float*)(ws + 31207424);            // [1]
  float*          qbk   = (float*)(ws + 31207680);            // [3200]
  unsigned short* kq    = (unsigned short*)(ws + 31224064);   // [3200][1024]
  unsigned short* vT    = (unsigned short*)(ws + 37777664);   // [32][1024][128]
  unsigned short* att   = (unsigned short*)(ws + 46166272);   // [32][576][128]
  unsigned short* qn    = (unsigned short*)d_out;             // bf16 scratch in output buf

  const float scale = 0.03125f;  // 1/sqrt(1024)

  // 1. weight prep: converts + V transpose + small vectors
  wconv_kernel<<<2560, 256, 0, stream>>>(q_w, k_w, qwb, kwb, scale);
  tpv_kernel<<<dim3(32, 48), dim3(32, 8), 0, stream>>>(v_w, v_wt);
  wvec_kernel<<<641, 256, 0, stream>>>(q_w, k_w, q_b, k_b, scale, bias3, w4, c4);

  // 2. LN box (shared stats, two outputs)
  ln_box_kernel<<<3200, 256, 0, stream>>>(box, k_ln_w, k_ln_b, v_ln_w, v_ln_b, kn, vn);

  // 3. W3 = qwb @ kwb^T  [1024][1536]
  gemm_w3_kernel<<<dim3(8, 12), 256, 0, stream>>>(qwb, kwb, W3);

  // 4. qbk = kn @ w4 + c4  [3200]
  qbk_kernel<<<800, 256, 0, stream>>>(kn, w4, c4, qbk);

  // 5. kq and vT projections, one grid
  gemm_kv_kernel<<<dim3(25, 8, 2), 256, 0, stream>>>(
      kn, vn, W3, v_wt, bias3, v_b, kq, vT);

  // 6. LN vit -> qn (scratch in d_out)
  ln_vit_kernel<<<18432, 256, 0, stream>>>(vit, q_ln_w, q_ln_b, qn);

  // 7. attention scores + masked softmax -> bf16 att [B][576][128]
  att1_kernel<<<dim3(9, 32), 256, 0, stream>>>(qn, kq, qbk, lengths, att);

  // 8. out = att @ v + vit
  att2_kernel<<<dim3(5, 8, 32), 256, 0, stream>>>(att, vT, vit, out);

  (void)in_sizes; (void)n_in; (void)out_size; (void)ws_size;
}

// Round 8
// 178.376 us; speedup vs baseline: 1.3244x; 1.0453x over previous
//
#include <hip/hip_runtime.h>
#include <stdint.h>

typedef __attribute__((ext_vector_type(8))) short short8;
typedef __attribute__((ext_vector_type(4))) float f32x4;

#define NEG_FLT_MAX (-3.402823466e38f)

__device__ __forceinline__ unsigned short f2bf(float f) {
  uint32_t u = __float_as_uint(f);
  uint32_t r = (u + 0x7fffu + ((u >> 16) & 1u)) >> 16;
  return (unsigned short)r;
}

__device__ __forceinline__ float bf2f(unsigned short u) {
  return __uint_as_float(((uint32_t)u) << 16);
}

__device__ __forceinline__ void gload16(const void* g, void* l) {
  __builtin_amdgcn_global_load_lds(
      (const __attribute__((address_space(1))) uint32_t*)g,
      (__attribute__((address_space(3))) uint32_t*)l, 16, 0, 0);
}

// ---------------- V weight transpose: [1536][1024] f32 -> [1024][1536] bf16 ----------
__global__ void tpv_kernel(const float* __restrict__ src, unsigned short* __restrict__ dst) {
  __shared__ float tile[32][33];
  const int c0 = blockIdx.x * 32;
  const int r0 = blockIdx.y * 32;
  const int tx = threadIdx.x, ty = threadIdx.y;  // 32 x 8
#pragma unroll
  for (int i = ty; i < 32; i += 8)
    tile[i][tx] = src[(size_t)(r0 + i) * 1024 + (c0 + tx)];
  __syncthreads();
#pragma unroll
  for (int i = ty; i < 32; i += 8)
    dst[(size_t)(c0 + i) * 1536 + (r0 + tx)] = f2bf(tile[tx][i]);
}

// ---------------- weight converts: q_w -> bf16, k_w*scale -> bf16 ----
__global__ __launch_bounds__(256) void wconv_kernel(
    const float* __restrict__ qw, const float* __restrict__ kw,
    unsigned short* __restrict__ qwb, unsigned short* __restrict__ kwb, float scale) {
  const int idx = blockIdx.x * 256 + threadIdx.x;
  const int QG = 1024 * 1024 / 4;
  if (idx < QG) {
    float4 v = ((const float4*)qw)[idx];
    ushort4 o;
    o.x = f2bf(v.x); o.y = f2bf(v.y); o.z = f2bf(v.z); o.w = f2bf(v.w);
    ((ushort4*)qwb)[idx] = o;
  } else {
    const int j = idx - QG;
    float4 v = ((const float4*)kw)[j];
    ushort4 o;
    o.x = f2bf(v.x * scale); o.y = f2bf(v.y * scale);
    o.z = f2bf(v.z * scale); o.w = f2bf(v.w * scale);
    ((ushort4*)kwb)[j] = o;
  }
}

// ---------------- small weight vectors ----------------
__global__ __launch_bounds__(256) void wvec_kernel(
    const float* __restrict__ qw, const float* __restrict__ kw,
    const float* __restrict__ qb, const float* __restrict__ kb, float scale,
    float* __restrict__ bias3, float* __restrict__ w4, float* __restrict__ c4) {
  const int wv = threadIdx.x >> 6, l = threadIdx.x & 63;
  const int idx = blockIdx.x;
  float s = 0.f;
  if (idx < 256) {
    const int i = idx * 4 + wv;
    const float* row = qw + (size_t)i * 1024;
#pragma unroll
    for (int s0 = 0; s0 < 1024; s0 += 256) {
      float4 a = *(const float4*)(row + s0 + l * 4);
      float4 b = *(const float4*)(kb + s0 + l * 4);
      s += a.x * b.x + a.y * b.y + a.z * b.z + a.w * b.w;
    }
#pragma unroll
    for (int off = 32; off; off >>= 1) s += __shfl_xor(s, off);
    if (l == 0) bias3[i] = s * scale;
  } else if (idx < 640) {
    const int j = (idx - 256) * 4 + wv;
    const float* row = kw + (size_t)j * 1024;
#pragma unroll
    for (int s0 = 0; s0 < 1024; s0 += 256) {
      float4 a = *(const float4*)(row + s0 + l * 4);
      float4 b = *(const float4*)(qb + s0 + l * 4);
      s += a.x * b.x + a.y * b.y + a.z * b.z + a.w * b.w;
    }
#pragma unroll
    for (int off = 32; off; off >>= 1) s += __shfl_xor(s, off);
    if (l == 0) w4[j] = s * scale;
  } else if (wv == 0) {
#pragma unroll
    for (int s0 = 0; s0 < 1024; s0 += 256) {
      float4 a = *(const float4*)(qb + s0 + l * 4);
      float4 b = *(const float4*)(kb + s0 + l * 4);
      s += a.x * b.x + a.y * b.y + a.z * b.z + a.w * b.w;
    }
#pragma unroll
    for (int off = 32; off; off >>= 1) s += __shfl_xor(s, off);
    if (l == 0) *c4 = s * scale;
  }
}

// ---------------- block reduction helper ----------------
__device__ __forceinline__ void block_reduce2(float& s, float& ss, float* red) {
#pragma unroll
  for (int off = 32; off > 0; off >>= 1) {
    s += __shfl_xor(s, off);
    ss += __shfl_xor(ss, off);
  }
  const int wave = threadIdx.x >> 6;
  const int lane = threadIdx.x & 63;
  if (lane == 0) { red[wave * 2] = s; red[wave * 2 + 1] = ss; }
  __syncthreads();
  if (threadIdx.x == 0) {
    float a = 0.f, b = 0.f;
    for (int i = 0; i < 4; i++) { a += red[i * 2]; b += red[i * 2 + 1]; }
    red[0] = a; red[1] = b;
  }
  __syncthreads();
  s = red[0]; ss = red[1];
}

// ---------------- LN vit: [18432][1024] f32 -> bf16 ----------------
__global__ __launch_bounds__(256) void ln_vit_kernel(
    const float* __restrict__ x, const float* __restrict__ w,
    const float* __restrict__ b, unsigned short* __restrict__ out) {
  __shared__ float red[8];
  const int row = blockIdx.x;
  const int t = threadIdx.x;
  const float4 v = ((const float4*)(x + (size_t)row * 1024))[t];
  float s = v.x + v.y + v.z + v.w;
  float ss = v.x * v.x + v.y * v.y + v.z * v.z + v.w * v.w;
  block_reduce2(s, ss, red);
  const float m = s * (1.f / 1024.f);
  const float var = ss * (1.f / 1024.f) - m * m;
  const float rstd = rsqrtf(var + 1e-5f);
  const float4 w4 = ((const float4*)w)[t];
  const float4 b4 = ((const float4*)b)[t];
  ushort4 o;
  o.x = f2bf((v.x - m) * rstd * w4.x + b4.x);
  o.y = f2bf((v.y - m) * rstd * w4.y + b4.y);
  o.z = f2bf((v.z - m) * rstd * w4.z + b4.z);
  o.w = f2bf((v.w - m) * rstd * w4.w + b4.w);
  ((ushort4*)(out + (size_t)row * 1024))[t] = o;
}

// ---------------- LN box: [3200][1536] f32 -> two bf16 outputs ----------------
__global__ __launch_bounds__(256) void ln_box_kernel(
    const float* __restrict__ x,
    const float* __restrict__ kw, const float* __restrict__ kb,
    const float* __restrict__ vw, const float* __restrict__ vb,
    unsigned short* __restrict__ kn, unsigned short* __restrict__ vn) {
  __shared__ float red[8];
  const int row = blockIdx.x;
  const int t = threadIdx.x;
  const float4* xr = (const float4*)(x + (size_t)row * 1536);
  const float4 a = xr[t];
  float4 c = make_float4(0.f, 0.f, 0.f, 0.f);
  if (t < 128) c = xr[256 + t];
  float s = a.x + a.y + a.z + a.w + c.x + c.y + c.z + c.w;
  float ss = a.x * a.x + a.y * a.y + a.z * a.z + a.w * a.w +
             c.x * c.x + c.y * c.y + c.z * c.z + c.w * c.w;
  block_reduce2(s, ss, red);
  const float m = s * (1.f / 1536.f);
  const float var = ss * (1.f / 1536.f) - m * m;
  const float rstd = rsqrtf(var + 1e-5f);
  {
    const float4 w4 = ((const float4*)kw)[t];
    const float4 b4 = ((const float4*)kb)[t];
    ushort4 o;
    o.x = f2bf((a.x - m) * rstd * w4.x + b4.x);
    o.y = f2bf((a.y - m) * rstd * w4.y + b4.y);
    o.z = f2bf((a.z - m) * rstd * w4.z + b4.z);
    o.w = f2bf((a.w - m) * rstd * w4.w + b4.w);
    ((ushort4*)(kn + (size_t)row * 1536))[t] = o;
    const float4 w4v = ((const float4*)vw)[t];
    const float4 b4v = ((const float4*)vb)[t];
    o.x = f2bf((a.x - m) * rstd * w4v.x + b4v.x);
    o.y = f2bf((a.y - m) * rstd * w4v.y + b4v.y);
    o.z = f2bf((a.z - m) * rstd * w4v.z + b4v.z);
    o.w = f2bf((a.w - m) * rstd * w4v.w + b4v.w);
    ((ushort4*)(vn + (size_t)row * 1536))[t] = o;
  }
  if (t < 128) {
    const int t2 = 256 + t;
    const float4 w4 = ((const float4*)kw)[t2];
    const float4 b4 = ((const float4*)kb)[t2];
    ushort4 o;
    o.x = f2bf((c.x - m) * rstd * w4.x + b4.x);
    o.y = f2bf((c.y - m) * rstd * w4.y + b4.y);
    o.z = f2bf((c.z - m) * rstd * w4.z + b4.z);
    o.w = f2bf((c.w - m) * rstd * w4.w + b4.w);
    ((ushort4*)(kn + (size_t)row * 1536))[t2] = o;
    const float4 w4v = ((const float4*)vw)[t2];
    const float4 b4v = ((const float4*)vb)[t2];
    o.x = f2bf((c.x - m) * rstd * w4v.x + b4v.x);
    o.y = f2bf((c.y - m) * rstd * w4v.y + b4v.y);
    o.z = f2bf((c.z - m) * rstd * w4v.z + b4v.z);
    o.w = f2bf((c.w - m) * rstd * w4v.w + b4v.w);
    ((ushort4*)(vn + (size_t)row * 1536))[t2] = o;
  }
}

// ---------------- qbk[row] = kn[row,:]·w4 + c4 ----------------
__global__ __launch_bounds__(256) void qbk_kernel(
    const unsigned short* __restrict__ kn, const float* __restrict__ w4,
    const float* __restrict__ c4, float* __restrict__ qbk) {
  const int wv = threadIdx.x >> 6, l = threadIdx.x & 63;
  const int row = blockIdx.x * 4 + wv;
  const unsigned short* r = kn + (size_t)row * 1536;
  float s = 0.f;
#pragma unroll
  for (int s0 = 0; s0 < 1536; s0 += 512) {
    short8 v = *(const short8*)(r + s0 + l * 8);
    const float* wp = w4 + s0 + l * 8;
    float4 w0 = *(const float4*)wp;
    float4 w1 = *(const float4*)(wp + 4);
    s += bf2f((unsigned short)v[0]) * w0.x + bf2f((unsigned short)v[1]) * w0.y +
         bf2f((unsigned short)v[2]) * w0.z + bf2f((unsigned short)v[3]) * w0.w +
         bf2f((unsigned short)v[4]) * w1.x + bf2f((unsigned short)v[5]) * w1.y +
         bf2f((unsigned short)v[6]) * w1.z + bf2f((unsigned short)v[7]) * w1.w;
  }
#pragma unroll
  for (int off = 32; off; off >>= 1) s += __shfl_xor(s, off);
  if (l == 0) qbk[row] = s + *c4;
}

// ---------------- GEMM core, BK=64 (proven r5 structure) ----------
__device__ __forceinline__ void gemm_core64(
    const unsigned short* __restrict__ A, int lda, int rowmaxA, int tm0,
    const unsigned short* __restrict__ Bt, int ldb, int rowmaxB, int tn0,
    int K, unsigned short* As, unsigned short* Bs, f32x4 acc[4][4]) {
  const int tid = threadIdx.x;
  const int w = tid >> 6, l = tid & 63;
  const int wr = w >> 1, wc = w & 1;
  const int srow = (w << 4) + (l >> 2);
  const int scol = (l & 3) << 3;
  int ra0 = tm0 + srow;      if (ra0 > rowmaxA) ra0 = rowmaxA;
  int ra1 = tm0 + srow + 64; if (ra1 > rowmaxA) ra1 = rowmaxA;
  int rb0 = tn0 + srow;      if (rb0 > rowmaxB) rb0 = rowmaxB;
  int rb1 = tn0 + srow + 64; if (rb1 > rowmaxB) rb1 = rowmaxB;
  const unsigned short* pa0 = A + (size_t)ra0 * lda + scol;
  const unsigned short* pa1 = A + (size_t)ra1 * lda + scol;
  const unsigned short* pb0 = Bt + (size_t)rb0 * ldb + scol;
  const unsigned short* pb1 = Bt + (size_t)rb1 * ldb + scol;
  unsigned short* la0 = As + (w << 4) * 32;
  unsigned short* la1 = As + ((w << 4) + 64) * 32;
  unsigned short* lb0 = Bs + (w << 4) * 32;
  unsigned short* lb1 = Bs + ((w << 4) + 64) * 32;
  const int foff = ((l & 15) << 5) + ((l >> 4) << 3);
  const unsigned short* fa = As + (wr << 6) * 32 + foff;
  const unsigned short* fb = Bs + (wc << 6) * 32 + foff;
#pragma unroll
  for (int i = 0; i < 4; i++)
#pragma unroll
    for (int j = 0; j < 4; j++) acc[i][j] = (f32x4)0.0f;
  for (int k0 = 0; k0 < K; k0 += 64) {
    gload16(pa0 + k0, la0);
    gload16(pa1 + k0, la1);
    gload16(pb0 + k0, lb0);
    gload16(pb1 + k0, lb1);
    gload16(pa0 + k0 + 32, la0 + 4096);
    gload16(pa1 + k0 + 32, la1 + 4096);
    gload16(pb0 + k0 + 32, lb0 + 4096);
    gload16(pb1 + k0 + 32, lb1 + 4096);
    __syncthreads();
    {
      short8 a[4], b[4];
#pragma unroll
      for (int i = 0; i < 4; i++) a[i] = *(const short8*)(fa + i * 512);
#pragma unroll
      for (int j = 0; j < 4; j++) b[j] = *(const short8*)(fb + j * 512);
#pragma unroll
      for (int i = 0; i < 4; i++)
#pragma unroll
        for (int j = 0; j < 4; j++)
          acc[i][j] = __builtin_amdgcn_mfma_f32_16x16x32_bf16(a[i], b[j], acc[i][j], 0, 0, 0);
    }
    {
      short8 a[4], b[4];
#pragma unroll
      for (int i = 0; i < 4; i++) a[i] = *(const short8*)(fa + 4096 + i * 512);
#pragma unroll
      for (int j = 0; j < 4; j++) b[j] = *(const short8*)(fb + 4096 + j * 512);
#pragma unroll
      for (int i = 0; i < 4; i++)
#pragma unroll
        for (int j = 0; j < 4; j++)
          acc[i][j] = __builtin_amdgcn_mfma_f32_16x16x32_bf16(a[i], b[j], acc[i][j], 0, 0, 0);
    }
    __syncthreads();
  }
}

// ---------------- W3 = qwb @ kwb^T : [1024][1536] bf16 ----------
__global__ __launch_bounds__(256) void gemm_w3_kernel(
    const unsigned short* __restrict__ qwb, const unsigned short* __restrict__ kwb,
    unsigned short* __restrict__ W3) {
  __shared__ unsigned short As[128 * 64];
  __shared__ unsigned short Bs[128 * 64];
  const int tm0 = blockIdx.x * 128, tn0 = blockIdx.y * 128;
  f32x4 acc[4][4];
  gemm_core64(qwb, 1024, 1023, tm0, kwb, 1024, 1535, tn0, 1024, As, Bs, acc);
  const int tid = threadIdx.x;
  const int w = tid >> 6, l = tid & 63;
  const int wr = w >> 1, wc = w & 1;
#pragma unroll
  for (int i = 0; i < 4; i++) {
    const int row0 = tm0 + wr * 64 + i * 16 + (l >> 4) * 4;
#pragma unroll
    for (int j = 0; j < 4; j++) {
      const int col = tn0 + wc * 64 + j * 16 + (l & 15);
#pragma unroll
      for (int r = 0; r < 4; r++)
        W3[(size_t)(row0 + r) * 1536 + col] = f2bf(acc[i][j][r]);
    }
  }
}

// ---------------- kq + vT projections in one grid (z selects) ----------------
__global__ __launch_bounds__(256) void gemm_kv_kernel(
    const unsigned short* __restrict__ kn, const unsigned short* __restrict__ vn,
    const unsigned short* __restrict__ W3, const unsigned short* __restrict__ vwt,
    const float* __restrict__ bias3, const float* __restrict__ vb,
    unsigned short* __restrict__ kq, unsigned short* __restrict__ vT) {
  __shared__ unsigned short As[128 * 64];
  __shared__ unsigned short Bs[128 * 64];
  const int z = blockIdx.z;
  const unsigned short* A = z ? vn : kn;
  const unsigned short* Bt = z ? vwt : W3;
  const float* bias = z ? vb : bias3;
  const int M = 3200, N = 1024, K = 1536;
  const int tm0 = blockIdx.x * 128, tn0 = blockIdx.y * 128;
  f32x4 acc[4][4];
  gemm_core64(A, K, M - 1, tm0, Bt, K, N - 1, tn0, K, As, Bs, acc);
  const int tid = threadIdx.x;
  const int w = tid >> 6, l = tid & 63;
  const int wr = w >> 1, wc = w & 1;
#pragma unroll
  for (int i = 0; i < 4; i++) {
    const int row0 = tm0 + wr * 64 + i * 16 + (l >> 4) * 4;
#pragma unroll
    for (int j = 0; j < 4; j++) {
      const int col = tn0 + wc * 64 + j * 16 + (l & 15);
      const float bv = bias[col];
#pragma unroll
      for (int r = 0; r < 4; r++) {
        const int row = row0 + r;
        const float val = acc[i][j][r] + bv;
        if (!z) {
          kq[(size_t)row * N + col] = f2bf(val);
        } else {
          const int bb = row / 100;
          const int ll = row - bb * 100;
          vT[((size_t)bb * N + col) * 128 + ll] = f2bf(val);
        }
      }
    }
  }
}

// ================= Fused attention: QK^T + softmax + PV + residual =================
// Grid (9, 32). Per block: 64 q-rows, full 1024 out cols.
// LDS arena 53248 B:
//   phase A (QK^T): As [0,8K) + Bs [8K,24K) staging
//   phase B (softmax): Smat f32 [0,34816), invr @34816, qb_l @35072
//   phase C: P bf16 [64][128] @36864 (disjoint from Smat)
//   phase D (PV): BsV bf16 [128][128] @0 (aliases dead Smat); E f32 [64][128] @0 (aliases BsV)
__global__ __launch_bounds__(256) void attfused_kernel(
    const unsigned short* __restrict__ qn, const unsigned short* __restrict__ kq,
    const unsigned short* __restrict__ vT, const float* __restrict__ qbk,
    const int* __restrict__ lengths, const float* __restrict__ vit,
    float* __restrict__ out) {
  __shared__ __align__(16) char smem[53248];
  unsigned short* As = (unsigned short*)smem;
  unsigned short* Bs = (unsigned short*)(smem + 8192);
  float* Smat = (float*)smem;
  float* invr = (float*)(smem + 34816);
  float* qb_l = (float*)(smem + 35072);
  unsigned short* P = (unsigned short*)(smem + 36864);

  const int b = blockIdx.y;
  const int tm0 = blockIdx.x * 64;
  const int t = threadIdx.x;
  const int w = t >> 6, l = t & 63;
  if (t < 128) qb_l[t] = (t < 100) ? qbk[b * 100 + t] : 0.f;

  // ---- phase A: S = qn_tile @ kq^T ----
  const unsigned short* A = qn + (size_t)b * 576 * 1024;
  const unsigned short* B = kq + (size_t)b * 100 * 1024;
  const int sr = t >> 2;
  const int sc8 = (t & 3) << 3;
  const unsigned short* pa = A + (size_t)(tm0 + sr) * 1024 + sc8;
  const unsigned short* pb0 = B + (size_t)sr * 1024 + sc8;
  int rb1 = 64 + sr; if (rb1 > 99) rb1 = 99;
  const unsigned short* pb1 = B + (size_t)rb1 * 1024 + sc8;
  unsigned short* la = As + (w << 9);
  unsigned short* lb0 = Bs + (w << 9);
  unsigned short* lb1 = Bs + 2048 + (w << 9);
  const int foff = ((l & 15) << 5) + ((l >> 4) << 3);
  const unsigned short* fa = As + foff;
  const unsigned short* fb = Bs + (w << 5) * 32 + foff;

  f32x4 acc[4][2];
#pragma unroll
  for (int i = 0; i < 4; i++) { acc[i][0] = (f32x4)0.0f; acc[i][1] = (f32x4)0.0f; }

  for (int k0 = 0; k0 < 1024; k0 += 64) {
    gload16(pa + k0, la);
    gload16(pb0 + k0, lb0);
    gload16(pb1 + k0, lb1);
    gload16(pa + k0 + 32, la + 2048);
    gload16(pb0 + k0 + 32, lb0 + 4096);
    gload16(pb1 + k0 + 32, lb1 + 4096);
    __syncthreads();
    {
      short8 a[4], bf[2];
#pragma unroll
      for (int i = 0; i < 4; i++) a[i] = *(const short8*)(fa + i * 512);
#pragma unroll
      for (int j = 0; j < 2; j++) bf[j] = *(const short8*)(fb + j * 512);
#pragma unroll
      for (int i = 0; i < 4; i++)
#pragma unroll
        for (int j = 0; j < 2; j++)
          acc[i][j] = __builtin_amdgcn_mfma_f32_16x16x32_bf16(a[i], bf[j], acc[i][j], 0, 0, 0);
    }
    {
      short8 a[4], bf[2];
#pragma unroll
      for (int i = 0; i < 4; i++) a[i] = *(const short8*)(fa + 2048 + i * 512);
#pragma unroll
      for (int j = 0; j < 2; j++) bf[j] = *(const short8*)(fb + 4096 + j * 512);
#pragma unroll
      for (int i = 0; i < 4; i++)
#pragma unroll
        for (int j = 0; j < 2; j++)
          acc[i][j] = __builtin_amdgcn_mfma_f32_16x16x32_bf16(a[i], bf[j], acc[i][j], 0, 0, 0);
    }
    __syncthreads();
  }

  // ---- phase B: store S col-major (+ q-bias), masked softmax ----
#pragma unroll
  for (int i = 0; i < 4; i++) {
    const int r0 = i * 16 + (l >> 4) * 4;
#pragma unroll
    for (int j = 0; j < 2; j++) {
      const int c = (w << 5) + j * 16 + (l & 15);
      const float qb = qb_l[c];
#pragma unroll
      for (int rr = 0; rr < 4; rr++) Smat[c * 68 + r0 + rr] = acc[i][j][rr] + qb;
    }
  }
  __syncthreads();

  const int r = t >> 2, g = t & 3;
  const int len = lengths[b];
  float mx = NEG_FLT_MAX;
#pragma unroll
  for (int i = 0; i < 25; i++) {
    const int ll = g * 25 + i;
    const float v = (ll < len) ? Smat[ll * 68 + r] : NEG_FLT_MAX;
    mx = fmaxf(mx, v);
  }
  mx = fmaxf(mx, __shfl_xor(mx, 1));
  mx = fmaxf(mx, __shfl_xor(mx, 2));
  float sum = 0.f;
#pragma unroll
  for (int i = 0; i < 25; i++) {
    const int ll = g * 25 + i;
    const float v = (ll < len) ? Smat[ll * 68 + r] : NEG_FLT_MAX;
    const float e = __expf(v - mx);
    Smat[ll * 68 + r] = e;
    sum += e;
  }
  sum += __shfl_xor(sum, 1);
  sum += __shfl_xor(sum, 2);
  if (g == 0) invr[r] = 1.f / sum;
  __syncthreads();

  // ---- phase C: P[64][128] bf16 (masked cols zero) ----
  {
    const float inv = invr[r];
    ushort4* prow = (ushort4*)(P + r * 128);
#pragma unroll
    for (int j = 0; j < 8; j++) {
      const int c0 = g * 32 + j * 4;
      ushort4 o;
      o.x = (c0 + 0 < 100) ? f2bf(Smat[(c0 + 0) * 68 + r] * inv) : (unsigned short)0;
      o.y = (c0 + 1 < 100) ? f2bf(Smat[(c0 + 1) * 68 + r] * inv) : (unsigned short)0;
      o.z = (c0 + 2 < 100) ? f2bf(Smat[(c0 + 2) * 68 + r] * inv) : (unsigned short)0;
      o.w = (c0 + 3 < 100) ? f2bf(Smat[(c0 + 3) * 68 + r] * inv) : (unsigned short)0;
      prow[g * 8 + j] = o;
    }
  }
  __syncthreads();

  // ---- phase D: out_tile = P @ vT^T + vit (8 N-tiles of 128 cols) ----
  const unsigned short* vTb = vT + (size_t)b * 131072;
  const float* vitb = vit + ((size_t)b * 576 + tm0) * 1024;
  float* outb = out + ((size_t)b * 576 + tm0) * 1024;
  for (int nt = 0; nt < 8; ++nt) {
    // stage BsV = vT rows [nt*128, nt*128+128), ld=128
    {
      const unsigned short* src = vTb + (size_t)nt * 16384 + ((t >> 4) * 128) + ((t & 15) * 8);
#pragma unroll
      for (int i = 0; i < 8; i++)
        gload16(src + i * 2048, smem + i * 4096 + w * 1024);
    }
    __syncthreads();
    f32x4 acc2[4][2];
#pragma unroll
    for (int i = 0; i < 4; i++) { acc2[i][0] = (f32x4)0.0f; acc2[i][1] = (f32x4)0.0f; }
#pragma unroll
    for (int ks = 0; ks < 4; ks++) {
      short8 av[4], bv[2];
#pragma unroll
      for (int i = 0; i < 4; i++)
        av[i] = *(const short8*)(smem + 36864 + (i * 16 + (l & 15)) * 256 + ks * 64 + ((l >> 4) << 4));
#pragma unroll
      for (int j = 0; j < 2; j++)
        bv[j] = *(const short8*)(smem + (w * 32 + j * 16 + (l & 15)) * 256 + ks * 64 + ((l >> 4) << 4));
#pragma unroll
      for (int i = 0; i < 4; i++)
#pragma unroll
        for (int j = 0; j < 2; j++)
          acc2[i][j] = __builtin_amdgcn_mfma_f32_16x16x32_bf16(av[i], bv[j], acc2[i][j], 0, 0, 0);
    }
    __syncthreads();
    // write E (aliases BsV) [64][128] f32
    {
      float* E = (float*)smem;
#pragma unroll
      for (int i = 0; i < 4; i++) {
        const int row0 = i * 16 + (l >> 4) * 4;
#pragma unroll
        for (int j = 0; j < 2; j++) {
          const int col = w * 32 + j * 16 + (l & 15);
#pragma unroll
          for (int rr = 0; rr < 4; rr++) E[(row0 + rr) * 128 + col] = acc2[i][j][rr];
        }
      }
    }
    __syncthreads();
    // coalesced: out = E + vit
    {
#pragma unroll
      for (int m = 0; m < 8; m++) {
        const int row = m * 8 + (t >> 5);
        const int colb = (t & 31) * 4;
        float4 e = *(const float4*)(smem + row * 512 + colb * 4);
        const size_t gidx = (size_t)row * 1024 + nt * 128 + colb;
        float4 vv = *(const float4*)(vitb + gidx);
        e.x += vv.x; e.y += vv.y; e.z += vv.z; e.w += vv.w;
        *(float4*)(outb + gidx) = e;
      }
    }
    __syncthreads();
  }
}

extern "C" void kernel_launch(void* const* d_in, const int* in_sizes, int n_in,
                              void* d_out, int out_size, void* d_ws, size_t ws_size,
                              hipStream_t stream) {
  const float* vit = (const float*)d_in[0];
  const float* box = (const float*)d_in[1];
  const int* lengths = (const int*)d_in[2];
  const float* q_ln_w = (const float*)d_in[3];
  const float* q_ln_b = (const float*)d_in[4];
  const float* q_w = (const float*)d_in[5];
  const float* q_b = (const float*)d_in[6];
  const float* k_ln_w = (const float*)d_in[7];
  const float* k_ln_b = (const float*)d_in[8];
  const float* k_w = (const float*)d_in[9];
  const float* k_b = (const float*)d_in[10];
  const float* v_ln_w = (const float*)d_in[11];
  const float* v_ln_b = (const float*)d_in[12];
  const float* v_w = (const float*)d_in[13];
  const float* v_b = (const float*)d_in[14];
  float* out = (float*)d_out;
  char* ws = (char*)d_ws;

  // Arena [0, 37748736): buffers all dead before ln_vit writes qn over them.
  unsigned short* kn    = (unsigned short*)(ws + 0);          // [3200][1536]
  unsigned short* vn    = (unsigned short*)(ws + 9830400);    // [3200][1536]
  unsigned short* v_wt  = (unsigned short*)(ws + 19660800);   // [1024][1536]
  unsigned short* qwb   = (unsigned short*)(ws + 22806528);   // [1024][1024]
  unsigned short* kwb   = (unsigned short*)(ws + 24903680);   // [1536][1024] (scaled)
  unsigned short* W3    = (unsigned short*)(ws + 28049408);   // [1024][1536]
  float*          bias3 = (float*)(ws + 31195136);            // [1024]
  float*          w4    = (float*)(ws + 31199232);            // [1536]
  float*          c4    = (float*)(ws + 31207424);            // [1]
  unsigned short* qn    = (unsigned short*)(ws + 0);          // [18432][1024] (arena reuse)
  // Outside arena (live into fused kernel):
  float*          qbk   = (float*)(ws + 37748736);            // [3200]
  unsigned short* kq    = (unsigned short*)(ws + 37761536);   // [3200][1024]
  unsigned short* vT    = (unsigned short*)(ws + 44315136);   // [32][1024][128]

  const float scale = 0.03125f;  // 1/sqrt(1024)

  // 1. weight prep
  wconv_kernel<<<2560, 256, 0, stream>>>(q_w, k_w, qwb, kwb, scale);
  tpv_kernel<<<dim3(32, 48), dim3(32, 8), 0, stream>>>(v_w, v_wt);
  wvec_kernel<<<641, 256, 0, stream>>>(q_w, k_w, q_b, k_b, scale, bias3, w4, c4);

  // 2. LN box
  ln_box_kernel<<<3200, 256, 0, stream>>>(box, k_ln_w, k_ln_b, v_ln_w, v_ln_b, kn, vn);

  // 3. W3 = qwb @ kwb^T
  gemm_w3_kernel<<<dim3(8, 12), 256, 0, stream>>>(qwb, kwb, W3);

  // 4. qbk = kn @ w4 + c4
  qbk_kernel<<<800, 256, 0, stream>>>(kn, w4, c4, qbk);

  // 5. kq and vT projections
  gemm_kv_kernel<<<dim3(25, 8, 2), 256, 0, stream>>>(
      kn, vn, W3, v_wt, bias3, v_b, kq, vT);

  // 6. LN vit -> qn (overwrites dead arena; after all arena readers)
  ln_vit_kernel<<<18432, 256, 0, stream>>>(vit, q_ln_w, q_ln_b, qn);

  // 7. fused attention: scores -> softmax -> @V -> +vit -> out
  attfused_kernel<<<dim3(9, 32), 256, 0, stream>>>(
      qn, kq, vT, qbk, lengths, vit, out);

  (void)in_sizes; (void)n_in; (void)out_size; (void)ws_size;
}